// Round 5
// baseline (72.815 us; speedup 1.0000x reference)
//
#include <hip/hip_runtime.h>
#include <math.h>

// Problem constants (fixed by the reference).
#define BB 4
#define SS 2048
#define DD 16
#define HH 16
#define NM 32  // Taylor moments m = 0..31

#define EXP2(x) __builtin_amdgcn_exp2f(x)
#define LOG2E 1.44269504088896340736f

__constant__ float INVFACT[NM] = {
    1.000000000e+00f, 1.000000000e+00f, 5.000000000e-01f, 1.666666667e-01f,
    4.166666667e-02f, 8.333333333e-03f, 1.388888889e-03f, 1.984126984e-04f,
    2.480158730e-05f, 2.755731922e-06f, 2.755731922e-07f, 2.505210839e-08f,
    2.087675699e-09f, 1.605904384e-10f, 1.147074560e-11f, 7.647163732e-13f,
    4.779477332e-14f, 2.811457254e-15f, 1.561920697e-16f, 8.220635247e-18f,
    4.110317623e-19f, 1.957294106e-20f, 8.896791392e-22f, 3.868170171e-23f,
    1.611737571e-24f, 6.446950284e-26f, 2.479596263e-27f, 9.183689864e-29f,
    3.279889237e-30f, 1.130996289e-31f, 3.769987629e-33f, 1.216125042e-34f};

#define UNPACK16(X4, XR)                                                   \
  const float4 x0_ = (X4)[0], x1_ = (X4)[1], x2_ = (X4)[2], x3_ = (X4)[3]; \
  const float XR[16] = {x0_.x, x0_.y, x0_.z, x0_.w, x1_.x, x1_.y, x1_.z,   \
                        x1_.w, x2_.x, x2_.y, x2_.z, x2_.w, x3_.x, x3_.y,   \
                        x3_.z, x3_.w};

// ---------------------------------------------------------------------------
// Fully fused kernel: grid = 64 bh x 4 sub = 256 blocks x 1024 thr
// (1 block/CU -> all 256 blocks co-resident; spin-wait is deadlock-free).
// Stages 1-4 as before (qkv staging, moment table, per-wave prefix row,
// polynomial + exact diagonal). NEW epilogue: projection done in-kernel.
//   - Every block stores its AO slice with agent-scope coherent stores,
//     then sets flags[(b,sub)*16+h] = 1 (device-scope release). Flags are
//     pre-zeroed by a 1 KB hipMemsetAsync (workspace is poisoned per iter).
//   - The h==0 block of each (b,sub) group spins on its 15 siblings'
//     flags (acquire), then computes out = AO @ w_out + b_out for its 512
//     rows from coherent AO loads. Proj of early groups overlaps the
//     still-running sub=3 blocks; one dispatch + kernel gap removed.
// ---------------------------------------------------------------------------
__global__ __launch_bounds__(1024) void fused_attn_kernel(
    const float* __restrict__ x, const float* __restrict__ w_qkv,
    const float* __restrict__ b_qkv, const float* __restrict__ w_out,
    const float* __restrict__ b_out, float* __restrict__ AO,
    unsigned* __restrict__ flags, float* __restrict__ out) {
  __shared__ float kl[SS];
  __shared__ float vl[SS];
  __shared__ float ql[512];
  __shared__ float2 SP[32 * 32];  // [jb][m] per-block moment sums (/m!)
  __shared__ float PR[8 * 64];    // per-wave prefix row (private to wave)
  __shared__ float wo[256];       // w_out [h][d] (proj epilogue)
  __shared__ float bo[16];

  const int blk = blockIdx.x;
  const int sub = blk & 3;
  const int bh = blk >> 2;
  const int b = bh >> 4, h = bh & 15;
  const int t = threadIdx.x;
  const int R = (sub + 1) * 512;  // k/v rows needed
  const int NB = (sub + 1) * 8;   // jb blocks needed
  const int q0 = sub * 512;       // first owned query
  const int grp = b * 4 + sub;    // flag group

  // Stage 1: k,v (and q for own range). Weights are block-uniform ->
  // scalar loads.
  {
    float wq[16], wk[16], wv[16];
#pragma unroll
    for (int i = 0; i < 16; ++i) {
      wq[i] = w_qkv[i * 48 + h];
      wk[i] = w_qkv[i * 48 + 16 + h];
      wv[i] = w_qkv[i * 48 + 32 + h];
    }
    const float bq = b_qkv[h], bk = b_qkv[16 + h], bv = b_qkv[32 + h];
    for (int r = 0; r * 1024 < R; ++r) {
      const int j = r * 1024 + t;
      if (j < R) {
        const float4* X4 = (const float4*)(x + ((size_t)b * SS + j) * DD);
        UNPACK16(X4, xr);
        float kk = bk, vv = bv;
#pragma unroll
        for (int i = 0; i < 16; ++i) {
          kk = fmaf(xr[i], wk[i], kk);
          vv = fmaf(xr[i], wv[i], vv);
        }
        kl[j] = kk;
        vl[j] = vv;
        if ((unsigned)(j - q0) < 512u) {  // wave-uniform (512-aligned)
          float qq = bq;
#pragma unroll
          for (int i = 0; i < 16; ++i) qq = fmaf(xr[i], wq[i], qq);
          ql[j - q0] = qq;
        }
      }
    }
  }
  __syncthreads();

  // Stage 2: moments, 4 m's per thread via power chain.
  {
    const int jb = t >> 5;        // 0..31
    const int mg = (t >> 2) & 7;  // moment group: m = 4mg..4mg+3
    const int js = t & 3;         // j-slice (16 j's, float4-interleaved)
    if (jb < NB) {
      float s0 = 0.f, s1 = 0.f, s2 = 0.f, s3 = 0.f;
      float w0 = 0.f, w1 = 0.f, w2 = 0.f, w3 = 0.f;
      const float4* kp = (const float4*)(kl + jb * 64);
      const float4* vp = (const float4*)(vl + jb * 64);
#pragma unroll
      for (int u = 0; u < 4; ++u) {
        const float4 kk = kp[u * 4 + js];  // 4 bank-quads x 2-way: free
        const float4 vv = vp[u * 4 + js];
        const float ke[4] = {kk.x, kk.y, kk.z, kk.w};
        const float ve[4] = {vv.x, vv.y, vv.z, vv.w};
#pragma unroll
        for (int e = 0; e < 4; ++e) {
          const float k = ke[e], v = ve[e];
          const float k2 = k * k, k4 = k2 * k2, k8 = k4 * k4, k16 = k8 * k8;
          float p = (mg & 1) ? k4 : 1.f;  // masks loop-invariant (hoisted)
          p *= (mg & 2) ? k8 : 1.f;
          p *= (mg & 4) ? k16 : 1.f;      // p = k^(4*mg)
          s0 += p; w0 = fmaf(p, v, w0);
          p *= k;
          s1 += p; w1 = fmaf(p, v, w1);
          p *= k;
          s2 += p; w2 = fmaf(p, v, w2);
          p *= k;
          s3 += p; w3 = fmaf(p, v, w3);
        }
      }
      // Reduce the 4 j-slice lanes (bits 0-1 of t) -> all lanes hold sums.
      s0 += __shfl_xor(s0, 1); s0 += __shfl_xor(s0, 2);
      s1 += __shfl_xor(s1, 1); s1 += __shfl_xor(s1, 2);
      s2 += __shfl_xor(s2, 1); s2 += __shfl_xor(s2, 2);
      s3 += __shfl_xor(s3, 1); s3 += __shfl_xor(s3, 2);
      w0 += __shfl_xor(w0, 1); w0 += __shfl_xor(w0, 2);
      w1 += __shfl_xor(w1, 1); w1 += __shfl_xor(w1, 2);
      w2 += __shfl_xor(w2, 1); w2 += __shfl_xor(w2, 2);
      w3 += __shfl_xor(w3, 1); w3 += __shfl_xor(w3, 2);
      // Lane js writes moment m = 4mg + js.
      const int m = mg * 4 + js;
      const float c = INVFACT[m];
      const float ss = (js == 0) ? s0 : (js == 1) ? s1 : (js == 2) ? s2 : s3;
      const float tt = (js == 0) ? w0 : (js == 1) ? w1 : (js == 2) ? w2 : w3;
      SP[jb * 32 + m] = make_float2(ss * c, tt * c);
    }
  }
  __syncthreads();

  // Stage 3+4: per-wave prefix row, then attention. One query per thread
  // (t < 512); each wave covers exactly one q-block -> PR row and diagonal
  // kl/vl reads are wave-uniform broadcasts.
  if (t < 512) {
    const int l = t & 63;
    const int w = t >> 6;
    const int qb = (q0 >> 6) + w;  // this wave's global q-block

    // Prefix over full blocks jb < qb; lane l owns float component l.
    {
      const float* SPf = (const float*)SP;
      float run = 0.f;
      for (int jb = 0; jb < qb; ++jb) run += SPf[jb * 64 + l];
      PR[w * 64 + l] = run;
    }

    const int i = q0 + t;
    const float q = ql[t];
    const float qs = q * LOG2E;

    // 32-term polynomial from this wave's prefix row (broadcast b128
    // reads; zero row when qb == 0 contributes nothing).
    float num = 0.f, den = 0.f;
    {
      const float4* bc4 = (const float4*)(PR + w * 64);
      float p = 1.f;  // q^m
#pragma unroll
      for (int g = 0; g < 16; ++g) {
        const float4 st = bc4[g];  // (S_2g, T_2g, S_2g+1, T_2g+1)
        den = fmaf(p, st.x, den);
        num = fmaf(p, st.y, num);
        p *= q;
        den = fmaf(p, st.z, den);
        num = fmaf(p, st.w, num);
        p *= q;
      }
    }

    // Exact diagonal block (lane-predicated: j_local <= lane).
    float ld = 0.f, ad = 0.f;
    const float4* kd4 = (const float4*)(kl + qb * 64);
    const float4* vd4 = (const float4*)(vl + qb * 64);
#pragma unroll
    for (int g = 0; g < 16; ++g) {
      const float4 k4 = kd4[g], v4 = vd4[g];
      const int jj = 4 * g;
      float e;
      e = EXP2(qs * k4.x); e = (jj + 0 <= l) ? e : 0.f; ld += e; ad = fmaf(e, v4.x, ad);
      e = EXP2(qs * k4.y); e = (jj + 1 <= l) ? e : 0.f; ld += e; ad = fmaf(e, v4.y, ad);
      e = EXP2(qs * k4.z); e = (jj + 2 <= l) ? e : 0.f; ld += e; ad = fmaf(e, v4.z, ad);
      e = EXP2(qs * k4.w); e = (jj + 3 <= l) ? e : 0.f; ld += e; ad = fmaf(e, v4.w, ad);
    }

    const float res = (ad + num) / (ld + den);
    // Agent-scope coherent store: visible across XCDs once released.
    __hip_atomic_store(&AO[(size_t)bh * SS + i], res, __ATOMIC_RELAXED,
                       __HIP_MEMORY_SCOPE_AGENT);
  }
  // __syncthreads drains every wave's stores (vmcnt(0) before s_barrier).
  __syncthreads();
  if (t == 0)
    __hip_atomic_store(&flags[grp * 16 + h], 1u, __ATOMIC_RELEASE,
                       __HIP_MEMORY_SCOPE_AGENT);

  // ---- Proj epilogue: only the h==0 block of each (b,sub) group. ----
  if (h != 0) return;

  if (t < 256) wo[t] = w_out[t];
  if (t < 16) bo[t] = b_out[t];
  if (t < 16) {
    // Spin on sibling flags (own flag already 1). All 256 blocks are
    // co-resident (1 block/CU), so every flag will be set.
    while (__hip_atomic_load(&flags[grp * 16 + t], __ATOMIC_ACQUIRE,
                             __HIP_MEMORY_SCOPE_AGENT) == 0u) {
      __builtin_amdgcn_s_sleep(2);
    }
  }
  __syncthreads();

  // thread t: row = q0 + (t>>1), d in [8*(t&1), 8*(t&1)+8).
  {
    const int row = q0 + (t >> 1);
    const int d0 = (t & 1) * 8;
    float a[16];
#pragma unroll
    for (int hh = 0; hh < 16; ++hh)
      a[hh] = __hip_atomic_load(&AO[(size_t)(b * 16 + hh) * SS + row],
                                __ATOMIC_RELAXED, __HIP_MEMORY_SCOPE_AGENT);
    float y[8];
#pragma unroll
    for (int d = 0; d < 8; ++d) y[d] = bo[d0 + d];
#pragma unroll
    for (int hh = 0; hh < 16; ++hh)
#pragma unroll
      for (int d = 0; d < 8; ++d)
        y[d] = fmaf(a[hh], wo[hh * 16 + d0 + d], y[d]);
    float4* o4 = (float4*)(out + ((size_t)b * SS + row) * DD + d0);
    o4[0] = make_float4(y[0], y[1], y[2], y[3]);
    o4[1] = make_float4(y[4], y[5], y[6], y[7]);
  }
}

// ---------------------------------------------------------------------------
extern "C" void kernel_launch(void* const* d_in, const int* in_sizes, int n_in,
                              void* d_out, int out_size, void* d_ws,
                              size_t ws_size, hipStream_t stream) {
  const float* x = (const float*)d_in[0];       // [B,S,D]
  const float* w_qkv = (const float*)d_in[1];   // [D, 3D]
  const float* b_qkv = (const float*)d_in[2];   // [3D]
  const float* w_out = (const float*)d_in[3];   // [D, D]
  const float* b_out = (const float*)d_in[4];   // [D]
  float* out = (float*)d_out;                   // [B,S,D] fp32

  float* ws = (float*)d_ws;
  float* AO = ws;                               // [64 bh][2048 s] (512 KB)
  unsigned* flags = (unsigned*)(ws + 64 * SS);  // [16 grp][16 h] (1 KB)

  hipMemsetAsync(flags, 0, 256 * sizeof(unsigned), stream);
  fused_attn_kernel<<<256, 1024, 0, stream>>>(x, w_qkv, b_qkv, w_out, b_out,
                                              AO, flags, out);
}

// Round 6
// 70.228 us; speedup vs baseline: 1.0368x; 1.0368x over previous
//
#include <hip/hip_runtime.h>
#include <math.h>

// Problem constants (fixed by the reference).
#define BB 4
#define SS 2048
#define DD 16
#define HH 16
#define NM 32  // Taylor moments m = 0..31

#define EXP2(x) __builtin_amdgcn_exp2f(x)
#define LOG2E 1.44269504088896340736f

__constant__ float INVFACT[NM] = {
    1.000000000e+00f, 1.000000000e+00f, 5.000000000e-01f, 1.666666667e-01f,
    4.166666667e-02f, 8.333333333e-03f, 1.388888889e-03f, 1.984126984e-04f,
    2.480158730e-05f, 2.755731922e-06f, 2.755731922e-07f, 2.505210839e-08f,
    2.087675699e-09f, 1.605904384e-10f, 1.147074560e-11f, 7.647163732e-13f,
    4.779477332e-14f, 2.811457254e-15f, 1.561920697e-16f, 8.220635247e-18f,
    4.110317623e-19f, 1.957294106e-20f, 8.896791392e-22f, 3.868170171e-23f,
    1.611737571e-24f, 6.446950284e-26f, 2.479596263e-27f, 9.183689864e-29f,
    3.279889237e-30f, 1.130996289e-31f, 3.769987629e-33f, 1.216125042e-34f};

#define UNPACK16(X4, XR)                                                   \
  const float4 x0_ = (X4)[0], x1_ = (X4)[1], x2_ = (X4)[2], x3_ = (X4)[3]; \
  const float XR[16] = {x0_.x, x0_.y, x0_.z, x0_.w, x1_.x, x1_.y, x1_.z,   \
                        x1_.w, x2_.x, x2_.y, x2_.z, x2_.w, x3_.x, x3_.y,   \
                        x3_.z, x3_.w};

// ---------------------------------------------------------------------------
// Fused kernel, 4-way split: grid = 64 bh x 4 sub = 256 blocks x 1024 thr.
// Block (bh,sub) owns queries [sub*512, sub*512+512).
// Stage 1: k/v for rows [0, (sub+1)*512) -> LDS; q for own 512 rows.
// Stage 2: moment table SP[jb][m] = (sum_j k^m/m!, sum_j k^m v/m!).
//   Thread = (jb = t>>5, mg = (t>>2)&7, js = t&3): 4 consecutive moments
//   (m = 4mg..4mg+3) over 16 j's. Power chain p*=k amortizes k^m build to
//   ~5 VALU per (j,m) pair (was ~13). Partials reduced across the 4
//   j-slice lanes via shfl_xor(1), shfl_xor(2).
// Stage 3+4 fused, no serial scan: each stage-4 wave computes its OWN
//   prefix row (lane l sums SP component l over jb < qb, independent
//   pipelined reads), writes private PR[w], reads it back same-wave (no
//   barrier), then 32-term polynomial + exact exp2 diagonal block.
// 2 barriers total.
// NOTE (R5 post-mortem): in-kernel proj via agent-scope atomics + flag
// spin REGRESSED (+1.9 us) — coherent stores bypass L2 and the flag chain
// serializes on the slowest sub=3 block. Keep the separate proj dispatch.
// ---------------------------------------------------------------------------
__global__ __launch_bounds__(1024) void fused_attn_kernel(
    const float* __restrict__ x, const float* __restrict__ w_qkv,
    const float* __restrict__ b_qkv, float* __restrict__ AO) {
  __shared__ float kl[SS];
  __shared__ float vl[SS];
  __shared__ float ql[512];
  __shared__ float2 SP[32 * 32];  // [jb][m] per-block moment sums (/m!)
  __shared__ float PR[8 * 64];    // per-wave prefix row (private to wave)

  const int blk = blockIdx.x;
  const int sub = blk & 3;
  const int bh = blk >> 2;
  const int b = bh >> 4, h = bh & 15;
  const int t = threadIdx.x;
  const int R = (sub + 1) * 512;  // k/v rows needed
  const int NB = (sub + 1) * 8;   // jb blocks needed
  const int q0 = sub * 512;       // first owned query

  // Stage 1: k,v (and q for own range). Weights are block-uniform ->
  // scalar loads.
  {
    float wq[16], wk[16], wv[16];
#pragma unroll
    for (int i = 0; i < 16; ++i) {
      wq[i] = w_qkv[i * 48 + h];
      wk[i] = w_qkv[i * 48 + 16 + h];
      wv[i] = w_qkv[i * 48 + 32 + h];
    }
    const float bq = b_qkv[h], bk = b_qkv[16 + h], bv = b_qkv[32 + h];
    for (int r = 0; r * 1024 < R; ++r) {
      const int j = r * 1024 + t;
      if (j < R) {
        const float4* X4 = (const float4*)(x + ((size_t)b * SS + j) * DD);
        UNPACK16(X4, xr);
        float kk = bk, vv = bv;
#pragma unroll
        for (int i = 0; i < 16; ++i) {
          kk = fmaf(xr[i], wk[i], kk);
          vv = fmaf(xr[i], wv[i], vv);
        }
        kl[j] = kk;
        vl[j] = vv;
        if ((unsigned)(j - q0) < 512u) {  // wave-uniform (512-aligned)
          float qq = bq;
#pragma unroll
          for (int i = 0; i < 16; ++i) qq = fmaf(xr[i], wq[i], qq);
          ql[j - q0] = qq;
        }
      }
    }
  }
  __syncthreads();

  // Stage 2: moments, 4 m's per thread via power chain.
  {
    const int jb = t >> 5;        // 0..31
    const int mg = (t >> 2) & 7;  // moment group: m = 4mg..4mg+3
    const int js = t & 3;         // j-slice (16 j's, float4-interleaved)
    if (jb < NB) {
      float s0 = 0.f, s1 = 0.f, s2 = 0.f, s3 = 0.f;
      float w0 = 0.f, w1 = 0.f, w2 = 0.f, w3 = 0.f;
      const float4* kp = (const float4*)(kl + jb * 64);
      const float4* vp = (const float4*)(vl + jb * 64);
#pragma unroll
      for (int u = 0; u < 4; ++u) {
        const float4 kk = kp[u * 4 + js];  // 4 bank-quads x 2-way: free
        const float4 vv = vp[u * 4 + js];
        const float ke[4] = {kk.x, kk.y, kk.z, kk.w};
        const float ve[4] = {vv.x, vv.y, vv.z, vv.w};
#pragma unroll
        for (int e = 0; e < 4; ++e) {
          const float k = ke[e], v = ve[e];
          const float k2 = k * k, k4 = k2 * k2, k8 = k4 * k4, k16 = k8 * k8;
          float p = (mg & 1) ? k4 : 1.f;  // masks loop-invariant (hoisted)
          p *= (mg & 2) ? k8 : 1.f;
          p *= (mg & 4) ? k16 : 1.f;      // p = k^(4*mg)
          s0 += p; w0 = fmaf(p, v, w0);
          p *= k;
          s1 += p; w1 = fmaf(p, v, w1);
          p *= k;
          s2 += p; w2 = fmaf(p, v, w2);
          p *= k;
          s3 += p; w3 = fmaf(p, v, w3);
        }
      }
      // Reduce the 4 j-slice lanes (bits 0-1 of t) -> all lanes hold sums.
      s0 += __shfl_xor(s0, 1); s0 += __shfl_xor(s0, 2);
      s1 += __shfl_xor(s1, 1); s1 += __shfl_xor(s1, 2);
      s2 += __shfl_xor(s2, 1); s2 += __shfl_xor(s2, 2);
      s3 += __shfl_xor(s3, 1); s3 += __shfl_xor(s3, 2);
      w0 += __shfl_xor(w0, 1); w0 += __shfl_xor(w0, 2);
      w1 += __shfl_xor(w1, 1); w1 += __shfl_xor(w1, 2);
      w2 += __shfl_xor(w2, 1); w2 += __shfl_xor(w2, 2);
      w3 += __shfl_xor(w3, 1); w3 += __shfl_xor(w3, 2);
      // Lane js writes moment m = 4mg + js.
      const int m = mg * 4 + js;
      const float c = INVFACT[m];
      const float ss = (js == 0) ? s0 : (js == 1) ? s1 : (js == 2) ? s2 : s3;
      const float tt = (js == 0) ? w0 : (js == 1) ? w1 : (js == 2) ? w2 : w3;
      SP[jb * 32 + m] = make_float2(ss * c, tt * c);
    }
  }
  __syncthreads();

  // Stage 3+4: per-wave prefix row, then attention. One query per thread
  // (t < 512); each wave covers exactly one q-block -> PR row and diagonal
  // kl/vl reads are wave-uniform broadcasts.
  if (t < 512) {
    const int l = t & 63;
    const int w = t >> 6;
    const int qb = (q0 >> 6) + w;  // this wave's global q-block

    // Prefix over full blocks jb < qb; lane l owns float component l
    // (banks 2-way aliased across lanes: free). Reads independent ->
    // pipelined. Written to this wave's private PR row; read back below
    // same-wave (lgkmcnt ordering, no barrier needed).
    {
      const float* SPf = (const float*)SP;
      float run = 0.f;
      for (int jb = 0; jb < qb; ++jb) run += SPf[jb * 64 + l];
      PR[w * 64 + l] = run;
    }

    const int i = q0 + t;
    const float q = ql[t];
    const float qs = q * LOG2E;

    // 32-term polynomial from this wave's prefix row (broadcast b128
    // reads; zero row when qb == 0 contributes nothing).
    float num = 0.f, den = 0.f;
    {
      const float4* bc4 = (const float4*)(PR + w * 64);
      float p = 1.f;  // q^m
#pragma unroll
      for (int g = 0; g < 16; ++g) {
        const float4 st = bc4[g];  // (S_2g, T_2g, S_2g+1, T_2g+1)
        den = fmaf(p, st.x, den);
        num = fmaf(p, st.y, num);
        p *= q;
        den = fmaf(p, st.z, den);
        num = fmaf(p, st.w, num);
        p *= q;
      }
    }

    // Exact diagonal block (lane-predicated: j_local <= lane).
    float ld = 0.f, ad = 0.f;
    const float4* kd4 = (const float4*)(kl + qb * 64);
    const float4* vd4 = (const float4*)(vl + qb * 64);
#pragma unroll
    for (int g = 0; g < 16; ++g) {
      const float4 k4 = kd4[g], v4 = vd4[g];
      const int jj = 4 * g;
      float e;
      e = EXP2(qs * k4.x); e = (jj + 0 <= l) ? e : 0.f; ld += e; ad = fmaf(e, v4.x, ad);
      e = EXP2(qs * k4.y); e = (jj + 1 <= l) ? e : 0.f; ld += e; ad = fmaf(e, v4.y, ad);
      e = EXP2(qs * k4.z); e = (jj + 2 <= l) ? e : 0.f; ld += e; ad = fmaf(e, v4.z, ad);
      e = EXP2(qs * k4.w); e = (jj + 3 <= l) ? e : 0.f; ld += e; ad = fmaf(e, v4.w, ad);
    }

    AO[(size_t)bh * SS + i] = (ad + num) / (ld + den);  // coalesced
  }
}

// ---------------------------------------------------------------------------
// Kernel C: out = AO @ w_out + b_out. 512 blocks x 256 thr; block = 16 rows.
// ---------------------------------------------------------------------------
__global__ __launch_bounds__(256) void proj_kernel(
    const float* __restrict__ AO, const float* __restrict__ w,
    const float* __restrict__ bias, float* __restrict__ out) {
  __shared__ float wct[DD * 68];  // column d at wct[d*68 + i]
  __shared__ float aol[256];      // aol[row_l*16 + h]
  __shared__ float bs[DD];
  const int t = threadIdx.x;
  const int b = blockIdx.x >> 7;  // 128 blocks per batch
  const int s_base = (blockIdx.x * 16) & (SS - 1);

  wct[(t & 15) * 68 + (t >> 4)] = w[t];
  if (t < DD) bs[t] = bias[t];
  {
    const int h = t >> 4, row_l = t & 15;
    const int bh = b * HH + h;
    aol[row_l * 16 + h] = AO[(size_t)bh * SS + s_base + row_l];
  }
  __syncthreads();

  const int row_l = t >> 4, d = t & 15;
  const float4* ao4 = (const float4*)aol;
  const float4* wc4 = (const float4*)wct;

  float y = bs[d];
#pragma unroll
  for (int g = 0; g < 4; ++g) {
    const float4 xv = ao4[row_l * 4 + g];
    const float4 wv = wc4[d * 17 + g];
    y = fmaf(xv.x, wv.x, y);
    y = fmaf(xv.y, wv.y, y);
    y = fmaf(xv.z, wv.z, y);
    y = fmaf(xv.w, wv.w, y);
  }
  out[(size_t)blockIdx.x * 256 + t] = y;
}

// ---------------------------------------------------------------------------
extern "C" void kernel_launch(void* const* d_in, const int* in_sizes, int n_in,
                              void* d_out, int out_size, void* d_ws,
                              size_t ws_size, hipStream_t stream) {
  const float* x = (const float*)d_in[0];       // [B,S,D]
  const float* w_qkv = (const float*)d_in[1];   // [D, 3D]
  const float* b_qkv = (const float*)d_in[2];   // [3D]
  const float* w_out = (const float*)d_in[3];   // [D, D]
  const float* b_out = (const float*)d_in[4];   // [D]
  float* out = (float*)d_out;                   // [B,S,D] fp32

  float* AO = (float*)d_ws;  // [64 bh][2048 s] attention out (512 KB)

  fused_attn_kernel<<<256, 1024, 0, stream>>>(x, w_qkv, b_qkv, AO);
  proj_kernel<<<512, 256, 0, stream>>>(AO, w_out, b_out, out);
}